// Round 3
// baseline (376.449 us; speedup 1.0000x reference)
//
#include <hip/hip_runtime.h>
#include <math.h>

#define NN 1024
#define K 16

// -------------------- tiny weight transposes into workspace --------------------
// W1T[c][j] = W1[j][c]  (256x64),  b1T[f][r] = b1[r][f]  (64x16)
__global__ __launch_bounds__(256) void transpose_kernel(const float* __restrict__ W1,
                                                        const float* __restrict__ b1,
                                                        float* __restrict__ W1T,
                                                        float* __restrict__ b1T) {
    int idx = blockIdx.x * 256 + threadIdx.x;
    if (idx < 16384) {
        int c = idx >> 6, j = idx & 63;
        W1T[idx] = W1[j * 256 + c];
    } else if (idx < 16384 + 1024) {
        int i2 = idx - 16384;
        int f = i2 >> 4, r = i2 & 15;
        b1T[i2] = b1[r * 64 + f];
    }
}

// -------------------- Top-K (17 smallest per row of D) --------------------
__global__ __launch_bounds__(256) void topk_kernel(const float* __restrict__ D,
                                                   int* __restrict__ selfIdx,
                                                   int* __restrict__ nbrIdx) {
    int row  = blockIdx.x * 4 + (threadIdx.x >> 6);
    int lane = threadIdx.x & 63;
    const float* Drow = D + (size_t)row * NN;

    float v[16];
#pragma unroll
    for (int j = 0; j < 16; ++j) v[j] = Drow[j * 64 + lane];

    for (int t = 0; t < K + 1; ++t) {
        float bv = v[0]; int bj = 0;
#pragma unroll
        for (int j = 1; j < 16; ++j)
            if (v[j] < bv) { bv = v[j]; bj = j; }
        int bidx = bj * 64 + lane;
#pragma unroll
        for (int off = 32; off > 0; off >>= 1) {
            float ov = __shfl_xor(bv, off);
            int   oi = __shfl_xor(bidx, off);
            if (ov < bv || (ov == bv && oi < bidx)) { bv = ov; bidx = oi; }
        }
        if (lane == 0) {
            if (t == 0) selfIdx[row] = bidx;
            else        nbrIdx[row * K + (t - 1)] = bidx;
        }
        if ((bidx & 63) == lane) v[bidx >> 6] = INFINITY;
    }
}

// -------------------- main: lane = edge; weights via scalar ops --------------------
// One wave (64 threads) handles 4 nodes x 16 edges. Per-lane vectors needing
// runtime indexing live in padded LDS rows; accumulators are compile-time-
// indexed register arrays. Reductions are all in-lane (no shuffles).
__global__ __launch_bounds__(64, 1) void node_kernel(
    const float* __restrict__ h,
    const float* __restrict__ W0, const float* __restrict__ b0,
    const float* __restrict__ W1T, const float* __restrict__ b1T,
    const float* __restrict__ W2, const float* __restrict__ b2,
    const float* __restrict__ Wl, const float* __restrict__ bl,
    const int* __restrict__ selfIdx, const int* __restrict__ nbrIdx,
    float* __restrict__ out) {

    __shared__ float s_x1[64 * 65];   // [lane][65] : neighbor features
    __shared__ float s_lab[64 * 65];  // [lane][65] : lab vector
    __shared__ float s_x2[4 * 65];    // [node][65] : self features

    const int lane = threadIdx.x;     // 0..63
    const int nloc = lane >> 4;       // local node 0..3
    const int e    = lane & 15;       // edge within node
    const int bn   = blockIdx.x * 4 + nloc;          // 4096 nodes
    const float* hb = h + ((size_t)(bn >> 10) << 16);  // batch base (1024*64)

    const int self = selfIdx[bn];
    const int nb   = nbrIdx[bn * K + e];
    const float* px1 = hb + (size_t)nb * 64;
    const float* px2 = hb + (size_t)self * 64;

    // ---- stage x1 (and x2 per node) into LDS; compute d in-lane ----
    float d = 0.f;
#pragma unroll
    for (int c = 0; c < 16; ++c) {
        float4 a = *(const float4*)(px1 + c * 4);
        float4 b = *(const float4*)(px2 + c * 4);
        s_x1[lane * 65 + c * 4 + 0] = a.x;
        s_x1[lane * 65 + c * 4 + 1] = a.y;
        s_x1[lane * 65 + c * 4 + 2] = a.z;
        s_x1[lane * 65 + c * 4 + 3] = a.w;
        if (e == 0) {
            s_x2[nloc * 65 + c * 4 + 0] = b.x;
            s_x2[nloc * 65 + c * 4 + 1] = b.y;
            s_x2[nloc * 65 + c * 4 + 2] = b.z;
            s_x2[nloc * 65 + c * 4 + 3] = b.w;
        }
        float t0 = a.x - b.x, t1 = a.y - b.y, t2 = a.z - b.z, t3 = a.w - b.w;
        d += t0 * t0; d += t1 * t1; d += t2 * t2; d += t3 * t3;
    }
    __syncthreads();

    // ---- phase 1: lab = leakyReLU(lr @ W0 + b0); accumulators in regs ----
    float acc64[64];
#pragma unroll
    for (int f = 0; f < 64; ++f) acc64[f] = b0[f];
#pragma unroll 2
    for (int j = 0; j < 64; ++j) {
        float lrj = s_x1[lane * 65 + j] - s_x2[nloc * 65 + j];
        const float* w0r = W0 + j * 64;
#pragma unroll
        for (int f = 0; f < 64; ++f)
            acc64[f] = fmaf(lrj, w0r[f], acc64[f]);
    }
#pragma unroll
    for (int f = 0; f < 64; ++f) {
        float t = acc64[f];
        s_lab[lane * 65 + f] = (t > 0.f) ? t : 0.02f * t;
    }
    __syncthreads();

    // ---- phase 2: thl[r] = lab@Wl + bl ; b1x[r] = b1[r]·x1 ----
    float thl[16], b1x[16];
#pragma unroll
    for (int r = 0; r < 16; ++r) { thl[r] = bl[r]; b1x[r] = 0.f; }
#pragma unroll 2
    for (int f = 0; f < 64; ++f) {
        float lf = s_lab[lane * 65 + f];
        float xf = s_x1[lane * 65 + f];
        const float* wlr = Wl  + f * 16;
        const float* b1r = b1T + f * 16;
#pragma unroll
        for (int r = 0; r < 16; ++r) {
            thl[r] = fmaf(lf, wlr[r], thl[r]);
            b1x[r] = fmaf(xf, b1r[r], b1x[r]);
        }
    }

    // ---- q-loop: U, dots, xr, vq, xo ----
    float xo[64];
#pragma unroll
    for (int o = 0; o < 64; ++o) xo[o] = 0.f;

#pragma unroll 1
    for (int q = 0; q < 4; ++q) {
        // U[j] = sum_i x1[i] * W1[j][q*64+i]  (W1T[(q*64+i)*64+j] contiguous in j)
        float U[64];
#pragma unroll
        for (int j = 0; j < 64; ++j) U[j] = 0.f;
#pragma unroll 2
        for (int i = 0; i < 64; ++i) {
            float xi = s_x1[lane * 65 + i];
            const float* w1r = W1T + (q * 64 + i) * 64;
#pragma unroll
            for (int j = 0; j < 64; ++j)
                U[j] = fmaf(xi, w1r[j], U[j]);
        }

        // three rolled dots, all in-lane
        float d0 = 0.f, d32 = 0.f, d48 = 0.f;
#pragma unroll
        for (int g = 0; g < 64; ++g) {
            float ug = U[g];
            d0  = fmaf(s_lab[lane * 65 + g],               ug, d0);
            d32 = fmaf(s_lab[lane * 65 + ((g + 32) & 63)], ug, d32);
            d48 = fmaf(s_lab[lane * 65 + ((g + 16) & 63)], ug, d48);
        }

        // select b1x/thl at r = q, 4+q, 8+q, 12+q (compile-time reg indices)
        float b1xA = (q == 0) ? b1x[0]  : (q == 1) ? b1x[1]  : (q == 2) ? b1x[2]  : b1x[3];
        float b1xB = (q == 0) ? b1x[4]  : (q == 1) ? b1x[5]  : (q == 2) ? b1x[6]  : b1x[7];
        float b1xC = (q == 0) ? b1x[8]  : (q == 1) ? b1x[9]  : (q == 2) ? b1x[10] : b1x[11];
        float b1xD = (q == 0) ? b1x[12] : (q == 1) ? b1x[13] : (q == 2) ? b1x[14] : b1x[15];
        float thlA = (q == 0) ? thl[0]  : (q == 1) ? thl[1]  : (q == 2) ? thl[2]  : thl[3];
        float thlB = (q == 0) ? thl[4]  : (q == 1) ? thl[5]  : (q == 2) ? thl[6]  : thl[7];
        float thlC = (q == 0) ? thl[8]  : (q == 1) ? thl[9]  : (q == 2) ? thl[10] : thl[11];
        float thlD = (q == 0) ? thl[12] : (q == 1) ? thl[13] : (q == 2) ? thl[14] : thl[15];

        float xr0 = (d0  + b1xA) * thlA;
        float xr1 = (d32 + b1xB) * thlB;
        float xr2 = (d48 + b1xC) * thlC;
        float xr3 = (d0  + b1xD) * thlD;
        float s03 = xr0 + xr3;

        // vq[g] and output GEMV fused
#pragma unroll 2
        for (int g = 0; g < 64; ++g) {
            float vg = s_lab[lane * 65 + g] * s03;
            vg = fmaf(s_lab[lane * 65 + ((g + 32) & 63)], xr1, vg);
            vg = fmaf(s_lab[lane * 65 + ((g + 16) & 63)], xr2, vg);
            const float* w2r = W2 + g * 256 + q * 64;
#pragma unroll
            for (int o = 0; o < 64; ++o)
                xo[o] = fmaf(vg, w2r[o], xo[o]);
        }

        // b2 contribution: xr_p * b2[(4p+q)][o]
#pragma unroll
        for (int p = 0; p < 4; ++p) {
            float xrp = (p == 0) ? xr0 : (p == 1) ? xr1 : (p == 2) ? xr2 : xr3;
            const float* b2r = b2 + (p * 4 + q) * 64;
#pragma unroll
            for (int o = 0; o < 64; ++o)
                xo[o] = fmaf(xrp, b2r[o], xo[o]);
        }
    }

    // ---- weighted edge sum via LDS transpose (reuse s_x1) ----
    float expd = __expf(-d * 0.1f);
    __syncthreads();
#pragma unroll
    for (int o = 0; o < 64; ++o)
        s_x1[lane * 65 + o] = expd * xo[o];
    __syncthreads();

    const int o0 = (lane & 15) * 4;
    float r0 = 0.f, r1 = 0.f, r2 = 0.f, r3 = 0.f;
#pragma unroll
    for (int ee = 0; ee < 16; ++ee) {
        const float* row = &s_x1[(nloc * 16 + ee) * 65 + o0];
        r0 += row[0]; r1 += row[1]; r2 += row[2]; r3 += row[3];
    }
    float4 res;
    res.x = r0; res.y = r1; res.z = r2; res.w = r3;
    *(float4*)(out + (((size_t)blockIdx.x * 4 + nloc) << 6) + o0) = res;
}

extern "C" void kernel_launch(void* const* d_in, const int* in_sizes, int n_in,
                              void* d_out, int out_size, void* d_ws, size_t ws_size,
                              hipStream_t stream) {
    const float* h  = (const float*)d_in[0];
    const float* D  = (const float*)d_in[1];
    const float* W0 = (const float*)d_in[2];
    const float* b0 = (const float*)d_in[3];
    const float* W1 = (const float*)d_in[4];
    const float* b1 = (const float*)d_in[5];
    const float* W2 = (const float*)d_in[6];
    const float* b2 = (const float*)d_in[7];
    const float* Wl = (const float*)d_in[8];
    const float* bl = (const float*)d_in[9];
    float* out = (float*)d_out;

    int*   selfIdx = (int*)d_ws;               // 4096
    int*   nbrIdx  = selfIdx + 4096;           // 65536
    float* W1T     = (float*)(nbrIdx + 65536); // 16384 floats
    float* b1T     = W1T + 16384;              // 1024 floats

    transpose_kernel<<<68, 256, 0, stream>>>(W1, b1, W1T, b1T);
    topk_kernel<<<1024, 256, 0, stream>>>(D, selfIdx, nbrIdx);
    node_kernel<<<1024, 64, 0, stream>>>(h, W0, b0, W1T, b1T, W2, b2, Wl, bl,
                                         selfIdx, nbrIdx, out);
}

// Round 4
// 332.805 us; speedup vs baseline: 1.1311x; 1.1311x over previous
//
#include <hip/hip_runtime.h>
#include <math.h>

#define NN 1024
#define K 16

// -------------------- tiny weight transposes into workspace --------------------
// W1T[c][j] = W1[j][c]  (256x64),  b1T[f][r] = b1[r][f]  (64x16)
__global__ __launch_bounds__(256) void transpose_kernel(const float* __restrict__ W1,
                                                        const float* __restrict__ b1,
                                                        float* __restrict__ W1T,
                                                        float* __restrict__ b1T) {
    int idx = blockIdx.x * 256 + threadIdx.x;
    if (idx < 16384) {
        int c = idx >> 6, j = idx & 63;
        W1T[idx] = W1[j * 256 + c];
    } else if (idx < 16384 + 1024) {
        int i2 = idx - 16384;
        int f = i2 >> 4, r = i2 & 15;
        b1T[i2] = b1[r * 64 + f];
    }
}

// -------------------- Top-K (17 smallest per row of D) --------------------
__global__ __launch_bounds__(256) void topk_kernel(const float* __restrict__ D,
                                                   int* __restrict__ selfIdx,
                                                   int* __restrict__ nbrIdx) {
    int row  = blockIdx.x * 4 + (threadIdx.x >> 6);
    int lane = threadIdx.x & 63;
    const float* Drow = D + (size_t)row * NN;

    float v[16];
#pragma unroll
    for (int j = 0; j < 16; ++j) v[j] = Drow[j * 64 + lane];

    for (int t = 0; t < K + 1; ++t) {
        float bv = v[0]; int bj = 0;
#pragma unroll
        for (int j = 1; j < 16; ++j)
            if (v[j] < bv) { bv = v[j]; bj = j; }
        int bidx = bj * 64 + lane;
#pragma unroll
        for (int off = 32; off > 0; off >>= 1) {
            float ov = __shfl_xor(bv, off);
            int   oi = __shfl_xor(bidx, off);
            if (ov < bv || (ov == bv && oi < bidx)) { bv = ov; bidx = oi; }
        }
        if (lane == 0) {
            if (t == 0) selfIdx[row] = bidx;
            else        nbrIdx[row * K + (t - 1)] = bidx;
        }
        if ((bidx & 63) == lane) v[bidx >> 6] = INFINITY;
    }
}

// -------------------- main: lane = edge; weights via VECTOR loads --------------------
// One wave (64 threads) = 4 nodes x 16 edges. Per-edge vectors in padded LDS
// rows (own-row access only); weights stream through the vector pipe (opaque
// per-lane zero offset defeats scalarization -> global_load_dwordx4 broadcast).
__global__ __launch_bounds__(64, 1) void node_kernel(
    const float* __restrict__ h,
    const float* __restrict__ W0, const float* __restrict__ b0,
    const float* __restrict__ W1T, const float* __restrict__ b1T,
    const float* __restrict__ W2, const float* __restrict__ b2,
    const float* __restrict__ Wl, const float* __restrict__ bl,
    const int* __restrict__ selfIdx, const int* __restrict__ nbrIdx,
    float* __restrict__ out) {

    __shared__ float s_x1[64 * 65];   // [lane][65] : neighbor features x1
    __shared__ float s_lr[64 * 65];   // [lane][65] : lr, overwritten by lab

    const int lane = threadIdx.x;     // 0..63
    const int nloc = lane >> 4;       // local node 0..3
    const int e    = lane & 15;       // edge within node
    const int bn   = blockIdx.x * 4 + nloc;            // 4096 nodes
    const float* hb = h + ((size_t)(bn >> 10) << 16);  // batch base (1024*64)

    // opaque zero in a VGPR: compiler cannot prove uniformity -> vector loads
    const int zv = __builtin_amdgcn_ds_bpermute(0, (int)threadIdx.x);

    const float4* W0v = (const float4*)W0  + zv;
    const float4* W1v = (const float4*)W1T + zv;
    const float4* W2v = (const float4*)W2  + zv;
    const float4* Wlv = (const float4*)Wl  + zv;
    const float4* b1v = (const float4*)b1T + zv;
    const float4* b2v = (const float4*)b2  + zv;
    const float4* b0v = (const float4*)b0  + zv;
    const float4* blv = (const float4*)bl  + zv;

    const int self = selfIdx[bn];
    const int nb   = nbrIdx[bn * K + e];
    const float4* px1 = (const float4*)(hb + (size_t)nb * 64);
    const float4* px2 = (const float4*)(hb + (size_t)self * 64);

    // ---- stage x1 and lr; accumulate d in-lane ----
    float d = 0.f;
#pragma unroll
    for (int c = 0; c < 16; ++c) {
        float4 a = px1[c];
        float4 b = px2[c];
        float t0 = a.x - b.x, t1 = a.y - b.y, t2 = a.z - b.z, t3 = a.w - b.w;
        s_x1[lane * 65 + c * 4 + 0] = a.x;
        s_x1[lane * 65 + c * 4 + 1] = a.y;
        s_x1[lane * 65 + c * 4 + 2] = a.z;
        s_x1[lane * 65 + c * 4 + 3] = a.w;
        s_lr[lane * 65 + c * 4 + 0] = t0;
        s_lr[lane * 65 + c * 4 + 1] = t1;
        s_lr[lane * 65 + c * 4 + 2] = t2;
        s_lr[lane * 65 + c * 4 + 3] = t3;
        d += t0 * t0; d += t1 * t1; d += t2 * t2; d += t3 * t3;
    }

    // ---- phase 1: lab = leakyReLU(lr @ W0 + b0) ----
    float acc[64];
#pragma unroll
    for (int c = 0; c < 16; ++c) {
        float4 t = b0v[c];
        acc[c * 4 + 0] = t.x; acc[c * 4 + 1] = t.y;
        acc[c * 4 + 2] = t.z; acc[c * 4 + 3] = t.w;
    }
#pragma unroll 2
    for (int j = 0; j < 64; ++j) {
        float lrj = s_lr[lane * 65 + j];
#pragma unroll
        for (int c = 0; c < 16; ++c) {
            float4 wv = W0v[j * 16 + c];
            acc[c * 4 + 0] = fmaf(lrj, wv.x, acc[c * 4 + 0]);
            acc[c * 4 + 1] = fmaf(lrj, wv.y, acc[c * 4 + 1]);
            acc[c * 4 + 2] = fmaf(lrj, wv.z, acc[c * 4 + 2]);
            acc[c * 4 + 3] = fmaf(lrj, wv.w, acc[c * 4 + 3]);
        }
    }
#pragma unroll
    for (int f = 0; f < 64; ++f) {
        float t = acc[f];
        s_lr[lane * 65 + f] = (t > 0.f) ? t : 0.02f * t;   // own-row overwrite
    }

    // ---- phase 2: thl[r] = lab@Wl + bl ; b1x[r] = b1[r]·x1 ----
    float thl[16], b1x[16];
#pragma unroll
    for (int c = 0; c < 4; ++c) {
        float4 t = blv[c];
        thl[c * 4 + 0] = t.x; thl[c * 4 + 1] = t.y;
        thl[c * 4 + 2] = t.z; thl[c * 4 + 3] = t.w;
        b1x[c * 4 + 0] = 0.f; b1x[c * 4 + 1] = 0.f;
        b1x[c * 4 + 2] = 0.f; b1x[c * 4 + 3] = 0.f;
    }
#pragma unroll 2
    for (int f = 0; f < 64; ++f) {
        float lf = s_lr[lane * 65 + f];
        float xf = s_x1[lane * 65 + f];
#pragma unroll
        for (int c = 0; c < 4; ++c) {
            float4 wv = Wlv[f * 4 + c];
            float4 bv = b1v[f * 4 + c];
            thl[c * 4 + 0] = fmaf(lf, wv.x, thl[c * 4 + 0]);
            thl[c * 4 + 1] = fmaf(lf, wv.y, thl[c * 4 + 1]);
            thl[c * 4 + 2] = fmaf(lf, wv.z, thl[c * 4 + 2]);
            thl[c * 4 + 3] = fmaf(lf, wv.w, thl[c * 4 + 3]);
            b1x[c * 4 + 0] = fmaf(xf, bv.x, b1x[c * 4 + 0]);
            b1x[c * 4 + 1] = fmaf(xf, bv.y, b1x[c * 4 + 1]);
            b1x[c * 4 + 2] = fmaf(xf, bv.z, b1x[c * 4 + 2]);
            b1x[c * 4 + 3] = fmaf(xf, bv.w, b1x[c * 4 + 3]);
        }
    }

    // ---- q-loop: U, dots, xr, vq, xo ----
    float xo[64];
#pragma unroll
    for (int o = 0; o < 64; ++o) xo[o] = 0.f;

#pragma unroll 1
    for (int q = 0; q < 4; ++q) {
        // U[j] = sum_i x1[i] * W1T[(q*64+i)*64 + j]
        float U[64];
#pragma unroll
        for (int j = 0; j < 64; ++j) U[j] = 0.f;
#pragma unroll 2
        for (int i = 0; i < 64; ++i) {
            float xi = s_x1[lane * 65 + i];
#pragma unroll
            for (int c = 0; c < 16; ++c) {
                float4 wv = W1v[(q * 64 + i) * 16 + c];
                U[c * 4 + 0] = fmaf(xi, wv.x, U[c * 4 + 0]);
                U[c * 4 + 1] = fmaf(xi, wv.y, U[c * 4 + 1]);
                U[c * 4 + 2] = fmaf(xi, wv.z, U[c * 4 + 2]);
                U[c * 4 + 3] = fmaf(xi, wv.w, U[c * 4 + 3]);
            }
        }

        // rolled dots: 1 lab read + 3 FMA per g (U indices compile-time)
        float d0 = 0.f, d32 = 0.f, d48 = 0.f;
#pragma unroll
        for (int g = 0; g < 64; ++g) {
            float lg = s_lr[lane * 65 + g];
            d0  = fmaf(lg, U[g],             d0);
            d32 = fmaf(lg, U[(g + 32) & 63], d32);
            d48 = fmaf(lg, U[(g + 48) & 63], d48);
        }

        float b1xA = (q == 0) ? b1x[0]  : (q == 1) ? b1x[1]  : (q == 2) ? b1x[2]  : b1x[3];
        float b1xB = (q == 0) ? b1x[4]  : (q == 1) ? b1x[5]  : (q == 2) ? b1x[6]  : b1x[7];
        float b1xC = (q == 0) ? b1x[8]  : (q == 1) ? b1x[9]  : (q == 2) ? b1x[10] : b1x[11];
        float b1xD = (q == 0) ? b1x[12] : (q == 1) ? b1x[13] : (q == 2) ? b1x[14] : b1x[15];
        float thlA = (q == 0) ? thl[0]  : (q == 1) ? thl[1]  : (q == 2) ? thl[2]  : thl[3];
        float thlB = (q == 0) ? thl[4]  : (q == 1) ? thl[5]  : (q == 2) ? thl[6]  : thl[7];
        float thlC = (q == 0) ? thl[8]  : (q == 1) ? thl[9]  : (q == 2) ? thl[10] : thl[11];
        float thlD = (q == 0) ? thl[12] : (q == 1) ? thl[13] : (q == 2) ? thl[14] : thl[15];

        float xr0 = (d0  + b1xA) * thlA;
        float xr1 = (d32 + b1xB) * thlB;
        float xr2 = (d48 + b1xC) * thlC;
        float xr3 = (d0  + b1xD) * thlD;
        float s03 = xr0 + xr3;

        // vq build + output GEMV
#pragma unroll 2
        for (int g = 0; g < 64; ++g) {
            float vg = s_lr[lane * 65 + g] * s03;
            vg = fmaf(s_lr[lane * 65 + ((g + 32) & 63)], xr1, vg);
            vg = fmaf(s_lr[lane * 65 + ((g + 16) & 63)], xr2, vg);
#pragma unroll
            for (int c = 0; c < 16; ++c) {
                float4 wv = W2v[g * 64 + q * 16 + c];
                xo[c * 4 + 0] = fmaf(vg, wv.x, xo[c * 4 + 0]);
                xo[c * 4 + 1] = fmaf(vg, wv.y, xo[c * 4 + 1]);
                xo[c * 4 + 2] = fmaf(vg, wv.z, xo[c * 4 + 2]);
                xo[c * 4 + 3] = fmaf(vg, wv.w, xo[c * 4 + 3]);
            }
        }

        // b2 contribution
#pragma unroll
        for (int p = 0; p < 4; ++p) {
            float xrp = (p == 0) ? xr0 : (p == 1) ? xr1 : (p == 2) ? xr2 : xr3;
#pragma unroll
            for (int c = 0; c < 16; ++c) {
                float4 bv = b2v[(p * 4 + q) * 16 + c];
                xo[c * 4 + 0] = fmaf(xrp, bv.x, xo[c * 4 + 0]);
                xo[c * 4 + 1] = fmaf(xrp, bv.y, xo[c * 4 + 1]);
                xo[c * 4 + 2] = fmaf(xrp, bv.z, xo[c * 4 + 2]);
                xo[c * 4 + 3] = fmaf(xrp, bv.w, xo[c * 4 + 3]);
            }
        }
    }

    // ---- weighted edge sum via LDS transpose (reuse s_x1) ----
    float expd = __expf(-d * 0.1f);
    __syncthreads();
#pragma unroll
    for (int o = 0; o < 64; ++o)
        s_x1[lane * 65 + o] = expd * xo[o];
    __syncthreads();

    const int o0 = (lane & 15) * 4;
    float r0 = 0.f, r1 = 0.f, r2 = 0.f, r3 = 0.f;
#pragma unroll
    for (int ee = 0; ee < 16; ++ee) {
        const float* row = &s_x1[(nloc * 16 + ee) * 65 + o0];
        r0 += row[0]; r1 += row[1]; r2 += row[2]; r3 += row[3];
    }
    float4 res;
    res.x = r0; res.y = r1; res.z = r2; res.w = r3;
    *(float4*)(out + (((size_t)blockIdx.x * 4 + nloc) << 6) + o0) = res;
}

extern "C" void kernel_launch(void* const* d_in, const int* in_sizes, int n_in,
                              void* d_out, int out_size, void* d_ws, size_t ws_size,
                              hipStream_t stream) {
    const float* h  = (const float*)d_in[0];
    const float* D  = (const float*)d_in[1];
    const float* W0 = (const float*)d_in[2];
    const float* b0 = (const float*)d_in[3];
    const float* W1 = (const float*)d_in[4];
    const float* b1 = (const float*)d_in[5];
    const float* W2 = (const float*)d_in[6];
    const float* b2 = (const float*)d_in[7];
    const float* Wl = (const float*)d_in[8];
    const float* bl = (const float*)d_in[9];
    float* out = (float*)d_out;

    int*   selfIdx = (int*)d_ws;               // 4096
    int*   nbrIdx  = selfIdx + 4096;           // 65536
    float* W1T     = (float*)(nbrIdx + 65536); // 16384 floats
    float* b1T     = W1T + 16384;              // 1024 floats

    transpose_kernel<<<68, 256, 0, stream>>>(W1, b1, W1T, b1T);
    topk_kernel<<<1024, 256, 0, stream>>>(D, selfIdx, nbrIdx);
    node_kernel<<<1024, 64, 0, stream>>>(h, W0, b0, W1T, b1T, W2, b2, Wl, bl,
                                         selfIdx, nbrIdx, out);
}

// Round 5
// 61.974 us; speedup vs baseline: 6.0743x; 5.3701x over previous
//
#include <hip/hip_runtime.h>
#include <math.h>

#define NN 1024
#define K 16

typedef _Float16 f16;
typedef f16 f16x8 __attribute__((ext_vector_type(8)));
typedef float f32x4 __attribute__((ext_vector_type(4)));

// LDS layout (bytes): pre-fragmented f16 weight B-fragments (1KB each: 64 lanes x 16B)
#define W0F_OFF 0          // 8 frags  (kt2 x nt4)
#define W1F_OFF 8192       // 32 frags (q4 x kt2 x nt4)
#define W2F_OFF 40960      // 32 frags (q4 x kt2 x nt4)
#define WLF_OFF 73728      // 2 frags  (kt2)
#define B1F_OFF 75776      // 2 frags  (kt2)
#define BUF_OFF 77824      // per-wave [32][72] f16 = 4608 B
#define LDS_BYTES (77824 + 4*4608)

#define MFMA16(a,b,c) __builtin_amdgcn_mfma_f32_16x16x32_f16((a),(b),(c),0,0,0)

// -------------------- Top-K (17 smallest per row of D) --------------------
__global__ __launch_bounds__(256) void topk_kernel(const float* __restrict__ D,
                                                   int* __restrict__ selfIdx,
                                                   int* __restrict__ nbrIdx) {
    int row  = blockIdx.x * 4 + (threadIdx.x >> 6);
    int lane = threadIdx.x & 63;
    const float* Drow = D + (size_t)row * NN;

    float v[16];
#pragma unroll
    for (int j = 0; j < 16; ++j) v[j] = Drow[j * 64 + lane];

    for (int t = 0; t < K + 1; ++t) {
        float bv = v[0]; int bj = 0;
#pragma unroll
        for (int j = 1; j < 16; ++j)
            if (v[j] < bv) { bv = v[j]; bj = j; }
        int bidx = bj * 64 + lane;
#pragma unroll
        for (int off = 32; off > 0; off >>= 1) {
            float ov = __shfl_xor(bv, off);
            int   oi = __shfl_xor(bidx, off);
            if (ov < bv || (ov == bv && oi < bidx)) { bv = ov; bidx = oi; }
        }
        if (lane == 0) {
            if (t == 0) selfIdx[row] = bidx;
            else        nbrIdx[row * K + (t - 1)] = bidx;
        }
        if ((bidx & 63) == lane) v[bidx >> 6] = INFINITY;
    }
}

// -------------------- main: MFMA edge-batched GEMMs --------------------
// Block = 256 threads = 4 waves; wave = 2 nodes (32 edges = 2 M-tiles of 16).
// A-frag (16x16x32 f16): lane holds row=(l&15), k=kt*32+(l>>4)*8+i.
// C-frag: col=(l&15), row=(l>>4)*4+reg  [m89-verified, dtype-independent].
__global__ __launch_bounds__(256, 1) void node_kernel(
    const float* __restrict__ h,
    const float* __restrict__ W0, const float* __restrict__ b0,
    const float* __restrict__ W1, const float* __restrict__ b1,
    const float* __restrict__ W2, const float* __restrict__ b2,
    const float* __restrict__ Wl, const float* __restrict__ bl,
    const int* __restrict__ selfIdx, const int* __restrict__ nbrIdx,
    float* __restrict__ out) {

    __shared__ __attribute__((aligned(16))) unsigned char LDS[LDS_BYTES];

    const int tid  = threadIdx.x;
    const int wid  = tid >> 6;
    const int lane = tid & 63;
    const int lrow = lane & 15;
    const int kgrp = lane >> 4;

    // ---------- stage pre-fragmented f16 weights (fg is wave-uniform) ----------
#pragma unroll 1
    for (int it = 0; it < 19; ++it) {
        int c  = tid + it * 256;          // 0..4863 ; c&63 == lane
        int fg = c >> 6;                  // frag id 0..75 (uniform per wave)
        float src[8];
        if (fg < 8) {
            int kt = fg >> 2, nt = fg & 3;
            int n = nt * 16 + lrow;
#pragma unroll
            for (int i = 0; i < 8; ++i) {
                int k = kt * 32 + kgrp * 8 + i;
                src[i] = W0[k * 64 + n];
            }
        } else if (fg < 40) {
            int t = fg - 8;
            int q = t >> 3, kt = (t >> 2) & 1, nt = t & 3;
            int f = nt * 16 + lrow;
#pragma unroll
            for (int i = 0; i < 8; ++i) {
                int ki = kt * 32 + kgrp * 8 + i;
                src[i] = W1[f * 256 + q * 64 + ki];
            }
        } else if (fg < 72) {
            int t = fg - 40;
            int q = t >> 3, kt = (t >> 2) & 1, nt = t & 3;
            int o = nt * 16 + lrow;
#pragma unroll
            for (int i = 0; i < 8; ++i) {
                int g = kt * 32 + kgrp * 8 + i;
                src[i] = W2[g * 256 + q * 64 + o];
            }
        } else if (fg < 74) {
            int kt = fg - 72;
#pragma unroll
            for (int i = 0; i < 8; ++i) {
                int f = kt * 32 + kgrp * 8 + i;
                src[i] = Wl[f * 16 + lrow];
            }
        } else {
            int kt = fg - 74;
#pragma unroll
            for (int i = 0; i < 8; ++i) {
                int ii = kt * 32 + kgrp * 8 + i;
                src[i] = b1[lrow * 64 + ii];
            }
        }
        f16x8 v;
#pragma unroll
        for (int i = 0; i < 8; ++i) v[i] = (f16)src[i];
        *(f16x8*)(LDS + fg * 1024 + lane * 16) = v;
    }
    __syncthreads();

    f16* buf = (f16*)(LDS + BUF_OFF + wid * 4608);   // [32][72] f16

    const int n0 = blockIdx.x * 8 + wid * 2;

    // ---------- load x1/x2, build A-frags, compute d ----------
    f16x8 x1f[2][2], lrf[2][2];
    float dv[2];
#pragma unroll
    for (int mt = 0; mt < 2; ++mt) {
        int node = n0 + mt;
        const float* hb = h + ((size_t)(node >> 10) << 16);
        int self = selfIdx[node];
        int nb   = nbrIdx[node * 16 + lrow];
        float dp = 0.f;
#pragma unroll
        for (int kt = 0; kt < 2; ++kt) {
            const float* p1 = hb + nb * 64 + kt * 32 + kgrp * 8;
            const float* p2 = hb + self * 64 + kt * 32 + kgrp * 8;
            float4 a0 = *(const float4*)(p1);
            float4 a1 = *(const float4*)(p1 + 4);
            float4 s0 = *(const float4*)(p2);
            float4 s1 = *(const float4*)(p2 + 4);
            float xs[8] = {a0.x,a0.y,a0.z,a0.w,a1.x,a1.y,a1.z,a1.w};
            float ss[8] = {s0.x,s0.y,s0.z,s0.w,s1.x,s1.y,s1.z,s1.w};
#pragma unroll
            for (int i = 0; i < 8; ++i) {
                float t = xs[i] - ss[i];
                x1f[mt][kt][i] = (f16)xs[i];
                lrf[mt][kt][i] = (f16)t;
                dp = fmaf(t, t, dp);
            }
        }
        dp += __shfl_xor(dp, 16);
        dp += __shfl_xor(dp, 32);
        dv[mt] = dp;
    }

    // ---------- phase 1: lab = leakyReLU(lr @ W0 + b0) ----------
    f32x4 labf[2][4];
#pragma unroll
    for (int nt = 0; nt < 4; ++nt) {
        float bb = b0[nt * 16 + lrow];
        labf[0][nt] = (f32x4){bb, bb, bb, bb};
        labf[1][nt] = labf[0][nt];
    }
#pragma unroll
    for (int kt = 0; kt < 2; ++kt) {
#pragma unroll
        for (int nt = 0; nt < 4; ++nt) {
            f16x8 bf = *(const f16x8*)(LDS + W0F_OFF + (kt * 4 + nt) * 1024 + lane * 16);
            labf[0][nt] = MFMA16(lrf[0][kt], bf, labf[0][nt]);
            labf[1][nt] = MFMA16(lrf[1][kt], bf, labf[1][nt]);
        }
    }
#pragma unroll
    for (int mt = 0; mt < 2; ++mt)
#pragma unroll
        for (int nt = 0; nt < 4; ++nt)
#pragma unroll
            for (int j = 0; j < 4; ++j) {
                float v = labf[mt][nt][j];
                v = v > 0.f ? v : 0.02f * v;
                labf[mt][nt][j] = v;
                buf[(mt*16 + kgrp*4 + j) * 72 + nt*16 + lrow] = (f16)v;
            }

    // ---------- thl = lab@Wl + bl ; b1x = x1 @ b1^T ----------
    f32x4 thlf[2], b1xf[2];
    {
        float blv = bl[lrow];
        thlf[0] = (f32x4){blv, blv, blv, blv};
        thlf[1] = thlf[0];
        b1xf[0] = (f32x4){0.f, 0.f, 0.f, 0.f};
        b1xf[1] = b1xf[0];
#pragma unroll
        for (int kt = 0; kt < 2; ++kt) {
            f16x8 wl = *(const f16x8*)(LDS + WLF_OFF + kt * 1024 + lane * 16);
            f16x8 bb = *(const f16x8*)(LDS + B1F_OFF + kt * 1024 + lane * 16);
#pragma unroll
            for (int mt = 0; mt < 2; ++mt) {
                f16x8 la = *(const f16x8*)&buf[(mt*16 + lrow) * 72 + kt*32 + kgrp*8];
                thlf[mt] = MFMA16(la, wl, thlf[mt]);
                b1xf[mt] = MFMA16(x1f[mt][kt], bb, b1xf[mt]);
            }
        }
    }

    // ---------- q-loop ----------
    f32x4 xof[2][4];
#pragma unroll
    for (int nt = 0; nt < 4; ++nt) {
        xof[0][nt] = (f32x4){0.f, 0.f, 0.f, 0.f};
        xof[1][nt] = xof[0][nt];
    }

#pragma unroll 1
    for (int q = 0; q < 4; ++q) {
        // U_q = x1 @ W1_q
        f32x4 Uf[2][4];
#pragma unroll
        for (int nt = 0; nt < 4; ++nt) {
            Uf[0][nt] = (f32x4){0.f, 0.f, 0.f, 0.f};
            Uf[1][nt] = Uf[0][nt];
        }
#pragma unroll
        for (int kt = 0; kt < 2; ++kt)
#pragma unroll
            for (int nt = 0; nt < 4; ++nt) {
                f16x8 bf = *(const f16x8*)(LDS + W1F_OFF + (q*8 + kt*4 + nt) * 1024 + lane * 16);
                Uf[0][nt] = MFMA16(x1f[0][kt], bf, Uf[0][nt]);
                Uf[1][nt] = MFMA16(x1f[1][kt], bf, Uf[1][nt]);
            }

        // rolled dots: d_s[e] = sum_g lab[e,g]*U[e,(g+s)&63], s in {0,32,48} -> tile shifts {0,2,3}
        f32x4 dsv[2][3];
#pragma unroll
        for (int mt = 0; mt < 2; ++mt)
#pragma unroll
            for (int si = 0; si < 3; ++si) {
                const int ts = (si == 0) ? 0 : (si == 1) ? 2 : 3;
                f32x4 p = labf[mt][0] * Uf[mt][(0 + ts) & 3];
                p += labf[mt][1] * Uf[mt][(1 + ts) & 3];
                p += labf[mt][2] * Uf[mt][(2 + ts) & 3];
                p += labf[mt][3] * Uf[mt][(3 + ts) & 3];
#pragma unroll
                for (int m = 1; m <= 8; m <<= 1) {
#pragma unroll
                    for (int j = 0; j < 4; ++j) p[j] += __shfl_xor(p[j], m);
                }
                dsv[mt][si] = p;
            }

        // xr_p = (d_{s(p)} + b1x[4p+q]) * thl[4p+q], broadcast from col 4p+q
        f32x4 xr[2][4];
#pragma unroll
        for (int mt = 0; mt < 2; ++mt)
#pragma unroll
            for (int p = 0; p < 4; ++p) {
                const int si = (p == 1) ? 1 : (p == 2) ? 2 : 0;
                f32x4 cand = (dsv[mt][si] + b1xf[mt]) * thlf[mt];
                int srcl = (lane & 48) | (p * 4 + q);
#pragma unroll
                for (int j = 0; j < 4; ++j) xr[mt][p][j] = __shfl(cand[j], srcl);
            }

        // vq = lab*(xr0+xr3) + labroll32*xr1 + labroll48*xr2 ; write f16 A-staging
#pragma unroll
        for (int mt = 0; mt < 2; ++mt) {
            f32x4 x03 = xr[mt][0] + xr[mt][3];
#pragma unroll
            for (int nt = 0; nt < 4; ++nt) {
                f32x4 v = labf[mt][nt] * x03
                        + labf[mt][(nt + 2) & 3] * xr[mt][1]
                        + labf[mt][(nt + 1) & 3] * xr[mt][2];
#pragma unroll
                for (int j = 0; j < 4; ++j)
                    buf[(mt*16 + kgrp*4 + j) * 72 + nt*16 + lrow] = (f16)v[j];
            }
        }

        // xo += vq @ W2_q
#pragma unroll
        for (int kt = 0; kt < 2; ++kt) {
            f16x8 av0 = *(const f16x8*)&buf[(0*16 + lrow) * 72 + kt*32 + kgrp*8];
            f16x8 av1 = *(const f16x8*)&buf[(1*16 + lrow) * 72 + kt*32 + kgrp*8];
#pragma unroll
            for (int nt = 0; nt < 4; ++nt) {
                f16x8 bf = *(const f16x8*)(LDS + W2F_OFF + (q*8 + kt*4 + nt) * 1024 + lane * 16);
                xof[0][nt] = MFMA16(av0, bf, xof[0][nt]);
                xof[1][nt] = MFMA16(av1, bf, xof[1][nt]);
            }
        }

        // b2 term: xo[e,o] += sum_p xr_p[e] * b2[4p+q, o]
#pragma unroll
        for (int p = 0; p < 4; ++p) {
#pragma unroll
            for (int nt = 0; nt < 4; ++nt) {
                float bv = b2[(p*4 + q) * 64 + nt*16 + lrow];
                xof[0][nt] += xr[0][p] * bv;
                xof[1][nt] += xr[1][p] * bv;
            }
        }
    }

    // ---------- epilogue: weighted sum over the 16 edges of each node ----------
#pragma unroll
    for (int mt = 0; mt < 2; ++mt) {
        f32x4 ew;
#pragma unroll
        for (int j = 0; j < 4; ++j) {
            float dd = __shfl(dv[mt], kgrp * 4 + j);   // d for row kgrp*4+j
            ew[j] = __expf(-dd * 0.1f);
        }
        float cs[4];
#pragma unroll
        for (int nt = 0; nt < 4; ++nt) {
            f32x4 wp = xof[mt][nt] * ew;
            float s = wp[0] + wp[1] + wp[2] + wp[3];
            s += __shfl_xor(s, 16);
            s += __shfl_xor(s, 32);
            cs[nt] = s;
        }
        float v = (kgrp == 0) ? cs[0] : (kgrp == 1) ? cs[1] : (kgrp == 2) ? cs[2] : cs[3];
        out[(size_t)(n0 + mt) * 64 + lane] = v;
    }
}

extern "C" void kernel_launch(void* const* d_in, const int* in_sizes, int n_in,
                              void* d_out, int out_size, void* d_ws, size_t ws_size,
                              hipStream_t stream) {
    const float* h  = (const float*)d_in[0];
    const float* D  = (const float*)d_in[1];
    const float* W0 = (const float*)d_in[2];
    const float* b0 = (const float*)d_in[3];
    const float* W1 = (const float*)d_in[4];
    const float* b1 = (const float*)d_in[5];
    const float* W2 = (const float*)d_in[6];
    const float* b2 = (const float*)d_in[7];
    const float* Wl = (const float*)d_in[8];
    const float* bl = (const float*)d_in[9];
    float* out = (float*)d_out;

    int* selfIdx = (int*)d_ws;            // 4096 ints
    int* nbrIdx  = selfIdx + 4096;        // 65536 ints

    topk_kernel<<<1024, 256, 0, stream>>>(D, selfIdx, nbrIdx);
    node_kernel<<<512, 256, 0, stream>>>(h, W0, b0, W1, b1, W2, b2, Wl, bl,
                                         selfIdx, nbrIdx, out);
}

// Round 6
// 53.030 us; speedup vs baseline: 7.0988x; 1.1687x over previous
//
#include <hip/hip_runtime.h>
#include <math.h>

#define NN 1024
#define K 16

typedef _Float16 f16;
typedef f16 f16x8 __attribute__((ext_vector_type(8)));
typedef float f32x4 __attribute__((ext_vector_type(4)));

// fragment region byte offsets (within f16 frag buffer in d_ws)
#define W0F_OFF 0          // 8 frags  (kt2 x nt4)
#define W1F_OFF 8192       // 32 frags (q4 x kt2 x nt4)
#define W2F_OFF 40960      // 32 frags (q4 x kt2 x nt4)
#define WLF_OFF 73728      // 2 frags  (kt2)
#define B1F_OFF 75776      // 2 frags  (kt2)
#define FRAG_BYTES 77824   // 76 frags x 1KB

#define MFMA16(a,b,c) __builtin_amdgcn_mfma_f32_16x16x32_f16((a),(b),(c),0,0,0)

// -------------------- one-time weight fragmentation --------------------
// frag fg (1KB) = 64 lanes x 16B; B-frag for 16x16x32 f16:
// lane holds col=(l&15), k = kt*32 + (l>>4)*8 + i.
__global__ __launch_bounds__(256) void prep_kernel(const float* __restrict__ W0,
                                                   const float* __restrict__ W1,
                                                   const float* __restrict__ W2,
                                                   const float* __restrict__ Wl,
                                                   const float* __restrict__ b1,
                                                   f16* __restrict__ frag) {
    int c = blockIdx.x * 256 + threadIdx.x;   // 0..4863
    if (c >= 76 * 64) return;
    int fg   = c >> 6;
    int lane = c & 63;
    int lrow = lane & 15;
    int kgrp = lane >> 4;
    float src[8];
    if (fg < 8) {
        int kt = fg >> 2, nt = fg & 3;
        int n = nt * 16 + lrow;
#pragma unroll
        for (int i = 0; i < 8; ++i) src[i] = W0[(kt * 32 + kgrp * 8 + i) * 64 + n];
    } else if (fg < 40) {
        int t = fg - 8;
        int q = t >> 3, kt = (t >> 2) & 1, nt = t & 3;
        int f = nt * 16 + lrow;
#pragma unroll
        for (int i = 0; i < 8; ++i) src[i] = W1[f * 256 + q * 64 + kt * 32 + kgrp * 8 + i];
    } else if (fg < 72) {
        int t = fg - 40;
        int q = t >> 3, kt = (t >> 2) & 1, nt = t & 3;
        int o = nt * 16 + lrow;
#pragma unroll
        for (int i = 0; i < 8; ++i) src[i] = W2[(kt * 32 + kgrp * 8 + i) * 256 + q * 64 + o];
    } else if (fg < 74) {
        int kt = fg - 72;
#pragma unroll
        for (int i = 0; i < 8; ++i) src[i] = Wl[(kt * 32 + kgrp * 8 + i) * 16 + lrow];
    } else {
        int kt = fg - 74;
#pragma unroll
        for (int i = 0; i < 8; ++i) src[i] = b1[lrow * 64 + kt * 32 + kgrp * 8 + i];
    }
    f16x8 v;
#pragma unroll
    for (int i = 0; i < 8; ++i) v[i] = (f16)src[i];
    *(f16x8*)((unsigned char*)frag + fg * 1024 + lane * 16) = v;
}

// -------------------- Top-K (17 smallest per row of D) --------------------
__global__ __launch_bounds__(256) void topk_kernel(const float* __restrict__ D,
                                                   int* __restrict__ selfIdx,
                                                   int* __restrict__ nbrIdx) {
    int row  = blockIdx.x * 4 + (threadIdx.x >> 6);
    int lane = threadIdx.x & 63;
    const float* Drow = D + (size_t)row * NN;

    float v[16];
#pragma unroll
    for (int j = 0; j < 16; ++j) v[j] = Drow[j * 64 + lane];

    for (int t = 0; t < K + 1; ++t) {
        float bv = v[0]; int bj = 0;
#pragma unroll
        for (int j = 1; j < 16; ++j)
            if (v[j] < bv) { bv = v[j]; bj = j; }
        int bidx = bj * 64 + lane;
#pragma unroll
        for (int off = 32; off > 0; off >>= 1) {
            float ov = __shfl_xor(bv, off);
            int   oi = __shfl_xor(bidx, off);
            if (ov < bv || (ov == bv && oi < bidx)) { bv = ov; bidx = oi; }
        }
        if (lane == 0) {
            if (t == 0) selfIdx[row] = bidx;
            else        nbrIdx[row * K + (t - 1)] = bidx;
        }
        if ((bidx & 63) == lane) v[bidx >> 6] = INFINITY;
    }
}

// -------------------- main: 1 wave per block = 2 nodes (32 edges) --------------------
// Weight B-frags read directly from global frag buffer (coalesced dwordx4,
// L2-resident). LDS = per-wave 4.6KB transpose buffer only. No barriers.
__global__ __launch_bounds__(64) void node_kernel(
    const float* __restrict__ h,
    const float* __restrict__ b0, const float* __restrict__ b2,
    const float* __restrict__ bl,
    const f16* __restrict__ frag,
    const int* __restrict__ selfIdx, const int* __restrict__ nbrIdx,
    float* __restrict__ out) {

    __shared__ __attribute__((aligned(16))) f16 buf[32 * 72];

    const int lane = threadIdx.x;
    const int lrow = lane & 15;
    const int kgrp = lane >> 4;
    const unsigned char* fb = (const unsigned char*)frag;
    const int n0 = blockIdx.x * 2;

    // ---------- load x1/x2, build A-frags, compute d ----------
    f16x8 x1f[2][2], lrf[2][2];
    float dv[2];
#pragma unroll
    for (int mt = 0; mt < 2; ++mt) {
        int node = n0 + mt;
        const float* hb = h + ((size_t)(node >> 10) << 16);
        int self = selfIdx[node];
        int nb   = nbrIdx[node * 16 + lrow];
        float dp = 0.f;
#pragma unroll
        for (int kt = 0; kt < 2; ++kt) {
            const float* p1 = hb + nb * 64 + kt * 32 + kgrp * 8;
            const float* p2 = hb + self * 64 + kt * 32 + kgrp * 8;
            float4 a0 = *(const float4*)(p1);
            float4 a1 = *(const float4*)(p1 + 4);
            float4 s0 = *(const float4*)(p2);
            float4 s1 = *(const float4*)(p2 + 4);
            float xs[8] = {a0.x,a0.y,a0.z,a0.w,a1.x,a1.y,a1.z,a1.w};
            float ss[8] = {s0.x,s0.y,s0.z,s0.w,s1.x,s1.y,s1.z,s1.w};
#pragma unroll
            for (int i = 0; i < 8; ++i) {
                float t = xs[i] - ss[i];
                x1f[mt][kt][i] = (f16)xs[i];
                lrf[mt][kt][i] = (f16)t;
                dp = fmaf(t, t, dp);
            }
        }
        dp += __shfl_xor(dp, 16);
        dp += __shfl_xor(dp, 32);
        dv[mt] = dp;
    }

    // ---------- phase 1: lab = leakyReLU(lr @ W0 + b0) ----------
    f32x4 labf[2][4];
#pragma unroll
    for (int nt = 0; nt < 4; ++nt) {
        float bb = b0[nt * 16 + lrow];
        labf[0][nt] = (f32x4){bb, bb, bb, bb};
        labf[1][nt] = labf[0][nt];
    }
#pragma unroll
    for (int kt = 0; kt < 2; ++kt) {
#pragma unroll
        for (int nt = 0; nt < 4; ++nt) {
            f16x8 bf = *(const f16x8*)(fb + W0F_OFF + (kt * 4 + nt) * 1024 + lane * 16);
            labf[0][nt] = MFMA16(lrf[0][kt], bf, labf[0][nt]);
            labf[1][nt] = MFMA16(lrf[1][kt], bf, labf[1][nt]);
        }
    }
#pragma unroll
    for (int mt = 0; mt < 2; ++mt)
#pragma unroll
        for (int nt = 0; nt < 4; ++nt)
#pragma unroll
            for (int j = 0; j < 4; ++j) {
                float v = labf[mt][nt][j];
                v = v > 0.f ? v : 0.02f * v;
                labf[mt][nt][j] = v;
                buf[(mt*16 + kgrp*4 + j) * 72 + nt*16 + lrow] = (f16)v;
            }

    // ---------- thl = lab@Wl + bl ; b1x = x1 @ b1^T ----------
    f32x4 thlf[2], b1xf[2];
    {
        float blv = bl[lrow];
        thlf[0] = (f32x4){blv, blv, blv, blv};
        thlf[1] = thlf[0];
        b1xf[0] = (f32x4){0.f, 0.f, 0.f, 0.f};
        b1xf[1] = b1xf[0];
#pragma unroll
        for (int kt = 0; kt < 2; ++kt) {
            f16x8 wl = *(const f16x8*)(fb + WLF_OFF + kt * 1024 + lane * 16);
            f16x8 bb = *(const f16x8*)(fb + B1F_OFF + kt * 1024 + lane * 16);
#pragma unroll
            for (int mt = 0; mt < 2; ++mt) {
                f16x8 la = *(const f16x8*)&buf[(mt*16 + lrow) * 72 + kt*32 + kgrp*8];
                thlf[mt] = MFMA16(la, wl, thlf[mt]);
                b1xf[mt] = MFMA16(x1f[mt][kt], bb, b1xf[mt]);
            }
        }
    }

    // ---------- q-loop ----------
    f32x4 xof[2][4];
#pragma unroll
    for (int nt = 0; nt < 4; ++nt) {
        xof[0][nt] = (f32x4){0.f, 0.f, 0.f, 0.f};
        xof[1][nt] = xof[0][nt];
    }

#pragma unroll 1
    for (int q = 0; q < 4; ++q) {
        // U_q = x1 @ W1_q
        f32x4 Uf[2][4];
#pragma unroll
        for (int nt = 0; nt < 4; ++nt) {
            Uf[0][nt] = (f32x4){0.f, 0.f, 0.f, 0.f};
            Uf[1][nt] = Uf[0][nt];
        }
#pragma unroll
        for (int kt = 0; kt < 2; ++kt)
#pragma unroll
            for (int nt = 0; nt < 4; ++nt) {
                f16x8 bf = *(const f16x8*)(fb + W1F_OFF + (q*8 + kt*4 + nt) * 1024 + lane * 16);
                Uf[0][nt] = MFMA16(x1f[0][kt], bf, Uf[0][nt]);
                Uf[1][nt] = MFMA16(x1f[1][kt], bf, Uf[1][nt]);
            }

        // rolled dots: shifts {0,32,48} -> tile shifts {0,2,3}
        f32x4 dsv[2][3];
#pragma unroll
        for (int mt = 0; mt < 2; ++mt)
#pragma unroll
            for (int si = 0; si < 3; ++si) {
                const int ts = (si == 0) ? 0 : (si == 1) ? 2 : 3;
                f32x4 p = labf[mt][0] * Uf[mt][(0 + ts) & 3];
                p += labf[mt][1] * Uf[mt][(1 + ts) & 3];
                p += labf[mt][2] * Uf[mt][(2 + ts) & 3];
                p += labf[mt][3] * Uf[mt][(3 + ts) & 3];
#pragma unroll
                for (int m = 1; m <= 8; m <<= 1) {
#pragma unroll
                    for (int j = 0; j < 4; ++j) p[j] += __shfl_xor(p[j], m);
                }
                dsv[mt][si] = p;
            }

        // xr_p = (d_{s(p)} + b1x[4p+q]) * thl[4p+q], broadcast from col 4p+q
        f32x4 xr[2][4];
#pragma unroll
        for (int mt = 0; mt < 2; ++mt)
#pragma unroll
            for (int p = 0; p < 4; ++p) {
                const int si = (p == 1) ? 1 : (p == 2) ? 2 : 0;
                f32x4 cand = (dsv[mt][si] + b1xf[mt]) * thlf[mt];
                int srcl = (lane & 48) | (p * 4 + q);
#pragma unroll
                for (int j = 0; j < 4; ++j) xr[mt][p][j] = __shfl(cand[j], srcl);
            }

        // vq = lab*(xr0+xr3) + labroll32*xr1 + labroll48*xr2 ; stage as f16 A
#pragma unroll
        for (int mt = 0; mt < 2; ++mt) {
            f32x4 x03 = xr[mt][0] + xr[mt][3];
#pragma unroll
            for (int nt = 0; nt < 4; ++nt) {
                f32x4 v = labf[mt][nt] * x03
                        + labf[mt][(nt + 2) & 3] * xr[mt][1]
                        + labf[mt][(nt + 1) & 3] * xr[mt][2];
#pragma unroll
                for (int j = 0; j < 4; ++j)
                    buf[(mt*16 + kgrp*4 + j) * 72 + nt*16 + lrow] = (f16)v[j];
            }
        }

        // xo += vq @ W2_q
#pragma unroll
        for (int kt = 0; kt < 2; ++kt) {
            f16x8 av0 = *(const f16x8*)&buf[(0*16 + lrow) * 72 + kt*32 + kgrp*8];
            f16x8 av1 = *(const f16x8*)&buf[(1*16 + lrow) * 72 + kt*32 + kgrp*8];
#pragma unroll
            for (int nt = 0; nt < 4; ++nt) {
                f16x8 bf = *(const f16x8*)(fb + W2F_OFF + (q*8 + kt*4 + nt) * 1024 + lane * 16);
                xof[0][nt] = MFMA16(av0, bf, xof[0][nt]);
                xof[1][nt] = MFMA16(av1, bf, xof[1][nt]);
            }
        }

        // b2 term
#pragma unroll
        for (int p = 0; p < 4; ++p) {
#pragma unroll
            for (int nt = 0; nt < 4; ++nt) {
                float bv = b2[(p*4 + q) * 64 + nt*16 + lrow];
                xof[0][nt] += xr[0][p] * bv;
                xof[1][nt] += xr[1][p] * bv;
            }
        }
    }

    // ---------- epilogue: weighted sum over the 16 edges of each node ----------
#pragma unroll
    for (int mt = 0; mt < 2; ++mt) {
        f32x4 ew;
#pragma unroll
        for (int j = 0; j < 4; ++j) {
            float dd = __shfl(dv[mt], kgrp * 4 + j);
            ew[j] = __expf(-dd * 0.1f);
        }
        float cs[4];
#pragma unroll
        for (int nt = 0; nt < 4; ++nt) {
            f32x4 wp = xof[mt][nt] * ew;
            float s = wp[0] + wp[1] + wp[2] + wp[3];
            s += __shfl_xor(s, 16);
            s += __shfl_xor(s, 32);
            cs[nt] = s;
        }
        float v = (kgrp == 0) ? cs[0] : (kgrp == 1) ? cs[1] : (kgrp == 2) ? cs[2] : cs[3];
        out[(size_t)(n0 + mt) * 64 + lane] = v;
    }
}

extern "C" void kernel_launch(void* const* d_in, const int* in_sizes, int n_in,
                              void* d_out, int out_size, void* d_ws, size_t ws_size,
                              hipStream_t stream) {
    const float* h  = (const float*)d_in[0];
    const float* D  = (const float*)d_in[1];
    const float* W0 = (const float*)d_in[2];
    const float* b0 = (const float*)d_in[3];
    const float* W1 = (const float*)d_in[4];
    const float* b1 = (const float*)d_in[5];
    const float* W2 = (const float*)d_in[6];
    const float* b2 = (const float*)d_in[7];
    const float* Wl = (const float*)d_in[8];
    const float* bl = (const float*)d_in[9];
    float* out = (float*)d_out;

    int* selfIdx = (int*)d_ws;            // 4096 ints
    int* nbrIdx  = selfIdx + 4096;        // 65536 ints
    f16* frag    = (f16*)(nbrIdx + 65536);// 77824 bytes

    prep_kernel<<<19, 256, 0, stream>>>(W0, W1, W2, Wl, b1, frag);
    topk_kernel<<<1024, 256, 0, stream>>>(D, selfIdx, nbrIdx);
    node_kernel<<<2048, 64, 0, stream>>>(h, b0, b2, bl, frag,
                                         selfIdx, nbrIdx, out);
}